// Round 4
// baseline (192.499 us; speedup 1.0000x reference)
//
#include <hip/hip_runtime.h>

#define NN 20000
#define NE 320000
#define FD 128
#define KTOT 640   // 4*128 (relations) + 128 (root/self)
#define BM 32      // nodes per block in fused kernel

typedef float f32x4 __attribute__((ext_vector_type(4)));
typedef __bf16 bf16x8 __attribute__((ext_vector_type(8)));

__device__ __forceinline__ unsigned f2ord(float f) {
  unsigned u = __float_as_uint(f);
  return (u & 0x80000000u) ? ~u : (u | 0x80000000u);
}
__device__ __forceinline__ float ord2f(unsigned u) {
  return (u & 0x80000000u) ? __uint_as_float(u & 0x7FFFFFFFu) : __uint_as_float(~u);
}
__device__ __forceinline__ unsigned pkbf(float a, float b) {
  union { __bf16 h[2]; unsigned u; } p;
  p.h[0] = (__bf16)a; p.h[1] = (__bf16)b; return p.u;
}

// init deg/minmax + convert x (f32) -> xb (packed bf16 pairs). grid covers NN*FD/4.
__global__ void init_kernel(unsigned* mm, int* deg,
                            const float* __restrict__ x, unsigned* __restrict__ xb) {
  int i = blockIdx.x * blockDim.x + threadIdx.x;
  if (i == 0) { mm[0] = 0xFFFFFFFFu; mm[1] = 0u; }
  if (i < NN) deg[i] = 0;
  if (i < NN * FD / 4) {
    float4 v = *(const float4*)(x + (size_t)i * 4);
    uint2 p;
    p.x = pkbf(v.x, v.y);
    p.y = pkbf(v.z, v.w);
    *(uint2*)(xb + (size_t)i * 2) = p;
  }
}

// fused histogram + edge-weight min/max
__global__ void histmm_kernel(const int* __restrict__ dst, const float* __restrict__ ew,
                              int* deg, unsigned* mm) {
  __shared__ unsigned smn[256], smx[256];
  unsigned lmn = 0xFFFFFFFFu, lmx = 0u;
  for (int i = blockIdx.x * blockDim.x + threadIdx.x; i < NE; i += gridDim.x * blockDim.x) {
    atomicAdd(&deg[dst[i]], 1);
    unsigned o = f2ord(ew[i]);
    lmn = (o < lmn) ? o : lmn;
    lmx = (o > lmx) ? o : lmx;
  }
  smn[threadIdx.x] = lmn; smx[threadIdx.x] = lmx;
  __syncthreads();
  for (int s = 128; s > 0; s >>= 1) {
    if (threadIdx.x < s) {
      unsigned a = smn[threadIdx.x], b = smn[threadIdx.x + s];
      smn[threadIdx.x] = (b < a) ? b : a;
      unsigned c = smx[threadIdx.x], d = smx[threadIdx.x + s];
      smx[threadIdx.x] = (d > c) ? d : c;
    }
    __syncthreads();
  }
  if (threadIdx.x == 0) { atomicMin(&mm[0], smn[0]); atomicMax(&mm[1], smx[0]); }
}

__global__ void scan_kernel(const int* __restrict__ deg, int* offs, int* cursor) {
  __shared__ int part[1024];
  const int CH = (NN + 1023) / 1024;  // 20
  int t = threadIdx.x;
  int b = t * CH;
  int e = (b + CH < NN) ? (b + CH) : NN;
  int s = 0;
  for (int i = b; i < e; ++i) s += deg[i];
  part[t] = s;
  __syncthreads();
  for (int off = 1; off < 1024; off <<= 1) {
    int v = part[t];
    int add = (t >= off) ? part[t - off] : 0;
    __syncthreads();
    part[t] = v + add;
    __syncthreads();
  }
  int excl = (t == 0) ? 0 : part[t - 1];
  for (int i = b; i < e; ++i) { offs[i] = excl; cursor[i] = excl; excl += deg[i]; }
  if (t == 1023) offs[NN] = part[1023];
}

__global__ void fill_kernel(const int* __restrict__ src, const int* __restrict__ dst,
                            const int* __restrict__ et, const float* __restrict__ ew,
                            const unsigned* __restrict__ mm, int* cursor,
                            int2* __restrict__ ed) {
  int e = blockIdx.x * blockDim.x + threadIdx.x;
  if (e >= NE) return;
  float mn = ord2f(mm[0]), mx = ord2f(mm[1]);
  float inv = 1.0f / (mx - mn + 1e-8f);
  int d = dst[e];
  int pos = atomicAdd(&cursor[d], 1);
  ed[pos] = make_int2(src[e] | (et[e] << 28), __float_as_int((ew[e] - mn) * inv));
}

// both layers' B^T: wt[n][k] = bf16(k<512 ? W[k/128][k%128][n] : root[k-512][n])
__global__ void prep_wt_both(const float* __restrict__ W1, const float* __restrict__ r1,
                             const float* __restrict__ W2, const float* __restrict__ r2,
                             __bf16* __restrict__ wt1, __bf16* __restrict__ wt2) {
  int idx = blockIdx.x * blockDim.x + threadIdx.x;
  if (idx >= 2 * FD * KTOT) return;
  int which = idx / (FD * KTOT);
  int rem = idx % (FD * KTOT);
  int n = rem / KTOT, k = rem % KTOT;
  const float* W = which ? W2 : W1;
  const float* rt = which ? r2 : r1;
  __bf16* wt = which ? wt2 : wt1;
  float v = (k < 512) ? W[(size_t)k * FD + n] : rt[(size_t)(k - 512) * FD + n];
  wt[rem] = (__bf16)v;
}

// ---------------------------------------------------------------------------
// Fused aggregate + GEMM. Block = BM=32 nodes, 512 threads (8 waves).
// Phase 1: wave w aggregates nodes w*4..w*4+3 (bf16 gathers from xb) and
//          writes bf16 A-rows [32][640] into XOR-swizzled LDS.
// Phase 2: GEMM out[m][n] = A[m][:] @ wt[n][:] + bias[n]; B fragments loaded
//          per-step from global wt into registers (L2-resident) -> no B LDS,
//          no per-step barriers. Wave w -> rows (w>>2)*16.., cols (w&3)*32...
// Swizzle: physical_byte = logical_byte ^ ((row&7)<<4); applied identically
// on write (4B words: word ^ ((row&7)<<2)) and read (16B-granular) ->
// round-trip exact, ds_read_b128 conflict-free (8 distinct 16B slots x 4
// banks = 32 banks, 2-way only).
// ---------------------------------------------------------------------------
template <int BF16OUT>
__global__ __launch_bounds__(512, 2) void fused_kernel(
    const unsigned* __restrict__ xb,   // packed bf16 pairs [NN][64]
    const int* __restrict__ offs, const int2* __restrict__ ed,
    const __bf16* __restrict__ wt, const float* __restrict__ bias,
    float* __restrict__ outf, __bf16* __restrict__ outb) {
  __shared__ unsigned As32[BM * 320];   // 32 rows x 640 bf16 = 40 KB
  int tid = threadIdx.x;
  int wave = tid >> 6, lane = tid & 63;
  int wr = wave >> 2, wc = wave & 3;
  int m0 = blockIdx.x * BM;
  int rl = wr * 16 + (lane & 15);     // local output row this lane contributes to
  int kfe = (lane >> 4) * 8;          // k-slice elem offset within 32-elem step
  int c0 = wc * 32 + (lane & 15);     // first output col
  const f32x4 zz = {0.f, 0.f, 0.f, 0.f};

  // ---- layout probe: decode acc-slot -> (row,col) through the REAL A path.
  // P1: A[r][k]=r/32 (exact bf16), B=1 (regs)      -> slot value = local row.
  // P2: A=1 (regs), B regs = c/128 for lane's col  -> slot value = col/4.
  // Self-consistent under any HW lane->fragment mapping (see R2 derivation).
  unsigned rowpack = 0, colpack0 = 0, colpack1 = 0;
  {
    if (tid < 256) {
      int row = tid >> 3;
      int wl = (tid & 7) * 2;         // logical u32 word (k elems 0..31)
      unsigned val = pkbf((float)row * 0.03125f, (float)row * 0.03125f);
      int sw2 = (row & 7) << 2;
      As32[row * 320 + (wl ^ sw2)] = val;
      As32[row * 320 + ((wl + 1) ^ sw2)] = val;
    }
    __syncthreads();
    const char* Arow = (const char*)As32 + rl * 1280;
    int swb = (rl & 7) << 4;
    bf16x8 pa = *(const bf16x8*)(Arow + ((kfe * 2) ^ swb));
    bf16x8 ones, bp0, bp1;
#pragma unroll
    for (int i = 0; i < 8; ++i) ones[i] = (__bf16)1.0f;
    __bf16 c0v = (__bf16)((float)c0 * 0.0078125f);
    __bf16 c1v = (__bf16)((float)(c0 + 16) * 0.0078125f);
#pragma unroll
    for (int i = 0; i < 8; ++i) { bp0[i] = c0v; bp1[i] = c1v; }
    f32x4 P1 = __builtin_amdgcn_mfma_f32_16x16x32_bf16(pa, ones, zz, 0, 0, 0);
    f32x4 P2a = __builtin_amdgcn_mfma_f32_16x16x32_bf16(ones, bp0, zz, 0, 0, 0);
    f32x4 P2b = __builtin_amdgcn_mfma_f32_16x16x32_bf16(ones, bp1, zz, 0, 0, 0);
#pragma unroll
    for (int j = 0; j < 4; ++j) {
      rowpack |= ((unsigned)(int)(P1[j] + 0.5f)) << (8 * j);
      colpack0 |= ((unsigned)(int)(P2a[j] * 4.0f + 0.5f)) << (8 * j);
      colpack1 |= ((unsigned)(int)(P2b[j] * 4.0f + 0.5f)) << (8 * j);
    }
    __syncthreads();  // probe reads done before aggregation overwrites LDS
  }

  // ---- phase 1: aggregation into swizzled LDS ----
#define LOADP(E, P0, P1)                                                \
  do {                                                                  \
    int s_ = (E).x & 0x0FFFFFFF;                                        \
    unsigned u_ = xb[(size_t)s_ * 64 + lane];                           \
    P0 = __uint_as_float(u_ << 16);                                     \
    P1 = __uint_as_float(u_ & 0xFFFF0000u);                             \
  } while (0)
#define ACCP(E, P0, P1)                                                 \
  do {                                                                  \
    float w_ = __int_as_float((E).y);                                   \
    unsigned r_ = ((unsigned)(E).x) >> 28;                              \
    float w0_ = (r_ == 0) ? w_ : 0.f, w1_ = (r_ == 1) ? w_ : 0.f;       \
    float w2_ = (r_ == 2) ? w_ : 0.f, w3_ = (r_ == 3) ? w_ : 0.f;       \
    a00 += w0_ * (P0); a01 += w0_ * (P1);                               \
    a10 += w1_ * (P0); a11 += w1_ * (P1);                               \
    a20 += w2_ * (P0); a21 += w2_ * (P1);                               \
    a30 += w3_ * (P0); a31 += w3_ * (P1);                               \
  } while (0)

  for (int nl = 0; nl < 4; ++nl) {
    int nloc = (wave << 2) + nl;
    int node = m0 + nloc;
    int beg = offs[node], end = offs[node + 1];
    float a00 = 0.f, a01 = 0.f, a10 = 0.f, a11 = 0.f;
    float a20 = 0.f, a21 = 0.f, a30 = 0.f, a31 = 0.f;
    int j = beg;
    for (; j + 4 <= end; j += 4) {
      int2 e0 = ed[j], e1 = ed[j + 1], e2 = ed[j + 2], e3 = ed[j + 3];
      float p00, p01, p10, p11, p20, p21, p30, p31;
      LOADP(e0, p00, p01); LOADP(e1, p10, p11);
      LOADP(e2, p20, p21); LOADP(e3, p30, p31);
      ACCP(e0, p00, p01); ACCP(e1, p10, p11);
      ACCP(e2, p20, p21); ACCP(e3, p30, p31);
    }
    for (; j < end; ++j) {
      int2 e = ed[j];
      float p0, p1;
      LOADP(e, p0, p1);
      ACCP(e, p0, p1);
    }
    int sw2 = (nloc & 7) << 2;
    unsigned* row = As32 + nloc * 320;
    row[(0 * 64 + lane) ^ sw2] = pkbf(a00, a01);
    row[(1 * 64 + lane) ^ sw2] = pkbf(a10, a11);
    row[(2 * 64 + lane) ^ sw2] = pkbf(a20, a21);
    row[(3 * 64 + lane) ^ sw2] = pkbf(a30, a31);
    row[(4 * 64 + lane) ^ sw2] = xb[(size_t)node * 64 + lane];  // root/self
  }
#undef LOADP
#undef ACCP
  __syncthreads();

  // ---- phase 2: GEMM, zero barriers in K-loop ----
  f32x4 acc0 = zz, acc1 = zz;
  const __bf16* w0p = wt + (size_t)c0 * KTOT + kfe;
  const __bf16* w1p = w0p + 16 * KTOT;
  const char* Arow = (const char*)As32 + rl * 1280;
  int swb = (rl & 7) << 4;
#pragma unroll
  for (int step = 0; step < 20; ++step) {
    int b = (step * 64 + kfe * 2) ^ swb;
    bf16x8 a = *(const bf16x8*)(Arow + b);
    bf16x8 b0 = *(const bf16x8*)(w0p + step * 32);
    bf16x8 b1 = *(const bf16x8*)(w1p + step * 32);
    acc0 = __builtin_amdgcn_mfma_f32_16x16x32_bf16(a, b0, acc0, 0, 0, 0);
    acc1 = __builtin_amdgcn_mfma_f32_16x16x32_bf16(a, b1, acc1, 0, 0, 0);
  }

  // ---- epilogue: probe-decoded slot -> (row, col) ----
#pragma unroll
  for (int j = 0; j < 4; ++j) {
    int rloc = (int)((rowpack >> (8 * j)) & 255u);
    size_t m = (size_t)(m0 + rloc);
    {
      int col = (int)((colpack0 >> (8 * j)) & 255u);
      float v = acc0[j] + bias[col];
      if (BF16OUT) outb[m * FD + col] = (__bf16)fmaxf(v, 0.f);
      else outf[m * FD + col] = v;
    }
    {
      int col = (int)((colpack1 >> (8 * j)) & 255u);
      float v = acc1[j] + bias[col];
      if (BF16OUT) outb[m * FD + col] = (__bf16)fmaxf(v, 0.f);
      else outf[m * FD + col] = v;
    }
  }
}

extern "C" void kernel_launch(void* const* d_in, const int* in_sizes, int n_in,
                              void* d_out, int out_size, void* d_ws, size_t ws_size,
                              hipStream_t stream) {
  const float* x  = (const float*)d_in[0];
  const int*   ei = (const int*)d_in[1];
  const int*   et = (const int*)d_in[2];
  const float* ew = (const float*)d_in[3];
  const float* W1 = (const float*)d_in[4];
  const float* r1 = (const float*)d_in[5];
  const float* b1 = (const float*)d_in[6];
  const float* W2 = (const float*)d_in[7];
  const float* r2 = (const float*)d_in[8];
  const float* b2 = (const float*)d_in[9];
  float* out = (float*)d_out;
  const int* src = ei;
  const int* dst = ei + NE;

  char* w = (char*)d_ws;
  size_t o = 0;
  auto take = [&](size_t bytes) -> char* {
    char* p = w + o;
    o += (bytes + 255) & ~(size_t)255;
    return p;
  };
  unsigned* mm  = (unsigned*)take(8);
  int* deg      = (int*)take((size_t)NN * 4);
  int* offs     = (int*)take((size_t)(NN + 1) * 4);
  int* cursor   = (int*)take((size_t)NN * 4);
  int2* ed      = (int2*)take((size_t)NE * 8);
  unsigned* xb  = (unsigned*)take((size_t)NN * 64 * 4);
  __bf16* h1    = (__bf16*)take((size_t)NN * FD * 2);
  __bf16* wt1   = (__bf16*)take((size_t)FD * KTOT * 2);
  __bf16* wt2   = (__bf16*)take((size_t)FD * KTOT * 2);
  (void)ws_size; (void)n_in; (void)in_sizes; (void)out_size;

  hipLaunchKernelGGL(init_kernel, dim3((NN * FD / 4 + 255) / 256), dim3(256), 0, stream,
                     mm, deg, x, xb);
  hipLaunchKernelGGL(histmm_kernel, dim3(512), dim3(256), 0, stream, dst, ew, deg, mm);
  hipLaunchKernelGGL(scan_kernel, dim3(1), dim3(1024), 0, stream, deg, offs, cursor);
  hipLaunchKernelGGL(fill_kernel, dim3((NE + 255) / 256), dim3(256), 0, stream,
                     src, dst, et, ew, mm, cursor, ed);
  hipLaunchKernelGGL(prep_wt_both, dim3((2 * FD * KTOT + 255) / 256), dim3(256), 0, stream,
                     W1, r1, W2, r2, wt1, wt2);
  // layer 1: aggregate(xb) + GEMM(wt1) + bias + relu -> h1 (bf16)
  hipLaunchKernelGGL((fused_kernel<1>), dim3(NN / BM), dim3(512), 0, stream,
                     xb, offs, ed, wt1, b1, (float*)nullptr, h1);
  // layer 2: aggregate(h1) + GEMM(wt2) + bias -> out (f32)
  hipLaunchKernelGGL((fused_kernel<0>), dim3(NN / BM), dim3(512), 0, stream,
                     (const unsigned*)h1, offs, ed, wt2, b2, out, (__bf16*)nullptr);
}